// Round 12
// baseline (2563.227 us; speedup 1.0000x reference)
//
#include <hip/hip_runtime.h>
#include <math.h>

// Problem dims
#define B_    64
#define LQ    512
#define LC    513          // with CLS
#define DD    512
#define HH    4
#define DH    128
#define DRr   128
#define NKEYS 10000
#define PP    96
#define TOPK  5
#define MROWS (B_*LC)      // 32832
#define VTSTRIDE 544       // padded LC for transposed V (multiple of 16)

typedef __attribute__((ext_vector_type(8))) short short8v;
typedef __attribute__((ext_vector_type(4))) float f32x4;
typedef __attribute__((ext_vector_type(16))) float f32x16;

static __device__ __forceinline__ float gelu_exact(float x) {
    return 0.5f * x * (1.0f + erff(x * 0.70710678118654752440f));
}

static __device__ __forceinline__ unsigned short f2bf(float x) {
    union { float f; unsigned u; } v; v.f = x;
    unsigned r = v.u + 0x7fff + ((v.u >> 16) & 1);
    return (unsigned short)(r >> 16);
}
static __device__ __forceinline__ float bf2f(unsigned short h) {
    union { float f; unsigned u; } v; v.u = ((unsigned)h) << 16;
    return v.f;
}
static __device__ __forceinline__ void split_bf(float x, unsigned short& hi, unsigned short& lo) {
    hi = f2bf(x);
    lo = f2bf(x - bf2f(hi));
}

// bijective XCD-aware swizzle (m204)
static __device__ __forceinline__ int xcd_swz(int orig, int nwg) {
    int xcd = orig & 7;
    int lid = orig >> 3;
    int q = nwg >> 3, r = nwg & 7;
    int base = (xcd < r) ? xcd * (q + 1) : r * (q + 1) + (xcd - r) * q;
    return base + lid;
}

// async global->LDS, 16B per lane. LDS dest linear: base + lane*16.
static __device__ __forceinline__ void gload16(const unsigned short* g, unsigned short* l) {
    __builtin_amdgcn_global_load_lds(
        (const __attribute__((address_space(1))) unsigned*)g,
        (__attribute__((address_space(3))) unsigned*)l, 16, 0, 0);
}

// ---------------- generic fp32 -> (hi,lo) bf16 split ----------------
__global__ __launch_bounds__(256)
void split_kernel(const float* __restrict__ x, unsigned short* __restrict__ hi,
                  unsigned short* __restrict__ lo, int n4)
{
    int i = blockIdx.x * blockDim.x + threadIdx.x;
    if (i >= n4) return;
    float4 v = ((const float4*)x)[i];
    unsigned short h0,h1,h2,h3,l0,l1,l2,l3;
    split_bf(v.x,h0,l0); split_bf(v.y,h1,l1); split_bf(v.z,h2,l2); split_bf(v.w,h3,l3);
    ((uint2*)hi)[i] = make_uint2((unsigned)h0 | ((unsigned)h1 << 16), (unsigned)h2 | ((unsigned)h3 << 16));
    ((uint2*)lo)[i] = make_uint2((unsigned)l0 | ((unsigned)l1 << 16), (unsigned)l2 | ((unsigned)l3 << 16));
}

// ---------------- concat cls + query -> h (wave per row) ----------------
__global__ __launch_bounds__(256)
void concat_cls(const float* __restrict__ query, const float* __restrict__ cls,
                float* __restrict__ h, unsigned short* __restrict__ h_hi,
                unsigned short* __restrict__ h_lo)
{
    int row = blockIdx.x * 4 + (threadIdx.x >> 6);
    int lane = threadIdx.x & 63;
    int b = row / LC, r = row - b * LC;
    const float* src = (r == 0) ? (cls + lane * 8)
                                : (query + ((size_t)b * LQ + (r - 1)) * DD + lane * 8);
    float4 v0 = *(const float4*)src;
    float4 v1 = *(const float4*)(src + 4);
    size_t o = (size_t)row * DD + lane * 8;
    *(float4*)(h + o) = v0;
    *(float4*)(h + o + 4) = v1;
    float vv[8] = {v0.x,v0.y,v0.z,v0.w,v1.x,v1.y,v1.z,v1.w};
    unsigned short hs[8], ls[8];
    #pragma unroll
    for (int i = 0; i < 8; i++) split_bf(vv[i], hs[i], ls[i]);
    uint4 hv, lv;
    hv.x = (unsigned)hs[0] | ((unsigned)hs[1] << 16);
    hv.y = (unsigned)hs[2] | ((unsigned)hs[3] << 16);
    hv.z = (unsigned)hs[4] | ((unsigned)hs[5] << 16);
    hv.w = (unsigned)hs[6] | ((unsigned)hs[7] << 16);
    lv.x = (unsigned)ls[0] | ((unsigned)ls[1] << 16);
    lv.y = (unsigned)ls[2] | ((unsigned)ls[3] << 16);
    lv.z = (unsigned)ls[4] | ((unsigned)ls[5] << 16);
    lv.w = (unsigned)ls[6] | ((unsigned)ls[7] << 16);
    *(uint4*)(h_hi + o) = hv;
    *(uint4*)(h_lo + o) = lv;
}

// ---------------- split-bf16 MFMA GEMM (32x32x16), round-6 structure ------
// MODE 0: C fp32 = acc + bias
// MODE 1: C fp32 = acc + bias + res
// MODE 2: (hi,lo) bf16 = gelu(acc + bias)
// MODE 3: QKV: col0<1024 -> qk hi/lo; col0>=1024 -> transposed V (interleaved)
#define BM 128
#define BN 128
#define BK 32

#define MFMA32(a, b, c) __builtin_amdgcn_mfma_f32_32x32x16_bf16(a, b, c, 0, 0, 0)

template<int MODE>
__global__ __launch_bounds__(256)
void gemm3(const unsigned short* __restrict__ Ahi, const unsigned short* __restrict__ Alo,
           const unsigned short* __restrict__ Whi, const unsigned short* __restrict__ Wlo,
           const float* __restrict__ bias, const float* __restrict__ res,
           float* __restrict__ Cf, unsigned short* __restrict__ Chi,
           unsigned short* __restrict__ Clo, unsigned* __restrict__ Vix,
           int M, int N, int K, int NBN)
{
    __shared__ __align__(16) unsigned short POOL[16384];   // 32KB

    const int t = threadIdx.x;
    const int lane = t & 63, w = t >> 6;
    const int wr = w >> 1, wc = w & 1;
    const int wg = xcd_swz(blockIdx.x, gridDim.x);
    const int bm = wg / NBN, bn = wg - bm * NBN;
    const int row0 = bm * BM, col0 = bn * BN;

    // staging coords: thread t covers (rows t>>2 and t>>2+64, 16B block t&3)
    const int srow = t >> 2;
    const int sg   = t & 3;
    const int glog = sg ^ (srow & 3);
    int ar0 = row0 + srow;      if (ar0 >= M) ar0 = M - 1;
    int ar1 = row0 + srow + 64; if (ar1 >= M) ar1 = M - 1;
    const size_t aoff0 = (size_t)ar0 * K + glog * 8;
    const size_t aoff1 = (size_t)ar1 * K + glog * 8;
    const size_t boff0 = (size_t)(col0 + srow) * K + glog * 8;
    const size_t boff1 = (size_t)(col0 + srow + 64) * K + glog * 8;
    const int ldso0 = t * 8;
    const int ldso1 = t * 8 + 2048;

    f32x16 acc[2][2];
    #pragma unroll
    for (int m = 0; m < 2; m++)
        #pragma unroll
        for (int n = 0; n < 2; n++)
            #pragma unroll
            for (int i = 0; i < 16; i++) acc[m][n][i] = 0.f;

    const int cl = lane & 31;
    const int kg = lane >> 5;
    const int cl3 = cl & 3;

    unsigned short* LAh = POOL;
    unsigned short* LAl = POOL + 4096;
    unsigned short* LBh = POOL + 8192;
    unsigned short* LBl = POOL + 12288;

    const int KT = K / BK;
    for (int kt = 0; kt < KT; kt++) {
        const int k0 = kt * BK;
        __syncthreads();
        gload16(Ahi + aoff0 + k0, &LAh[ldso0]);
        gload16(Ahi + aoff1 + k0, &LAh[ldso1]);
        gload16(Alo + aoff0 + k0, &LAl[ldso0]);
        gload16(Alo + aoff1 + k0, &LAl[ldso1]);
        gload16(Whi + boff0 + k0, &LBh[ldso0]);
        gload16(Whi + boff1 + k0, &LBh[ldso1]);
        gload16(Wlo + boff0 + k0, &LBl[ldso0]);
        gload16(Wlo + boff1 + k0, &LBl[ldso1]);
        __syncthreads();

        #pragma unroll
        for (int ks = 0; ks < 2; ks++) {
            const int blkswz = ((ks * 2 + kg) ^ cl3) * 8;
            short8v ah[2], al[2], bh[2], bl[2];
            #pragma unroll
            for (int m = 0; m < 2; m++) {
                int off = (wr * 64 + m * 32 + cl) * 32 + blkswz;
                ah[m] = *(const short8v*)&LAh[off];
                al[m] = *(const short8v*)&LAl[off];
            }
            #pragma unroll
            for (int n = 0; n < 2; n++) {
                int off = (wc * 64 + n * 32 + cl) * 32 + blkswz;
                bh[n] = *(const short8v*)&LBh[off];
                bl[n] = *(const short8v*)&LBl[off];
            }
            #pragma unroll
            for (int m = 0; m < 2; m++)
                #pragma unroll
                for (int n = 0; n < 2; n++) {
                    acc[m][n] = MFMA32(ah[m], bh[n], acc[m][n]);
                    acc[m][n] = MFMA32(al[m], bh[n], acc[m][n]);
                    acc[m][n] = MFMA32(ah[m], bl[n], acc[m][n]);
                }
        }
    }

    // ---- V-transpose epilogue (MODE3 blocks with col0 >= 1024) ----
    if (MODE == 3 && col0 >= 1024) {
        const int hh = (col0 - 1024) >> 7;
        unsigned* VS = (unsigned*)POOL;       // [32 dd][129] uints
        const int bb0 = row0 / LC;
        const int bound = (bb0 + 1) * LC;
        const int ddl = t >> 3, j0 = (t & 7) * 16;
        #pragma unroll
        for (int p = 0; p < 4; p++) {
            __syncthreads();
            if (wc == (p >> 1)) {
                const int ccl = col0 + wc * 64 + (p & 1) * 32 + cl;
                const float bcol = bias[ccl];
                #pragma unroll
                for (int m = 0; m < 2; m++) {
                    const int lrb = wr * 64 + m * 32 + 4 * kg;
                    #pragma unroll
                    for (int q = 0; q < 4; q++)
                        #pragma unroll
                        for (int r = 0; r < 4; r++) {
                            float v = ((p & 1) ? acc[m][1][q * 4 + r]
                                               : acc[m][0][q * 4 + r]) + bcol;
                            unsigned short hv, lv;
                            split_bf(v, hv, lv);
                            VS[cl * 129 + lrb + 8 * q + r] =
                                (unsigned)hv | ((unsigned)lv << 16);
                        }
                }
            }
            __syncthreads();
            long long vb0 = (long long)((bb0 * HH + hh) * DH + p * 32 + ddl) * VTSTRIDE
                            - (long long)bb0 * LC;
            long long vb1 = (long long)(((bb0 + 1) * HH + hh) * DH + p * 32 + ddl) * VTSTRIDE
                            - (long long)(bb0 + 1) * LC;
            #pragma unroll
            for (int j = 0; j < 16; j++) {
                int row = row0 + j0 + j;
                if (row < M) {
                    long long vi = (row < bound ? vb0 : vb1) + row;
                    Vix[vi] = VS[ddl * 129 + j0 + j];
                }
            }
        }
        return;
    }

    // ---- normal epilogue: col=lane&31, row=(reg&3)+8*(reg>>2)+4*(lane>>5)
    #pragma unroll
    for (int m = 0; m < 2; m++) {
        const int rb = row0 + wr * 64 + m * 32 + 4 * kg;
        #pragma unroll
        for (int n = 0; n < 2; n++) {
            const int cc = col0 + wc * 64 + n * 32 + cl;
            const float bcol = bias[cc];
            #pragma unroll
            for (int q = 0; q < 4; q++) {
                #pragma unroll
                for (int r = 0; r < 4; r++) {
                    int row = rb + 8 * q + r;
                    if (row < M) {
                        float v = acc[m][n][q * 4 + r] + bcol;
                        if (MODE == 1) v += res[(size_t)row * N + cc];
                        if (MODE == 2) {
                            v = gelu_exact(v);
                            unsigned short hv, lv;
                            split_bf(v, hv, lv);
                            Chi[(size_t)row * N + cc] = hv;
                            Clo[(size_t)row * N + cc] = lv;
                        } else if (MODE == 3) {
                            unsigned short hv, lv;
                            split_bf(v, hv, lv);
                            Chi[(size_t)row * 1024 + cc] = hv;
                            Clo[(size_t)row * 1024 + cc] = lv;
                        } else {
                            Cf[(size_t)row * N + cc] = v;
                        }
                    }
                }
            }
        }
    }
}

// ---------------- MFMA flash attention, split-bf16, async-staged ----------
#define AQT 64
#define AKT 32
#define NKT2 17
#define MFMA16(a, b, c) __builtin_amdgcn_mfma_f32_16x16x32_bf16(a, b, c, 0, 0, 0)
__global__ __launch_bounds__(256)
void attn_mfma(const unsigned short* __restrict__ qkhi, const unsigned short* __restrict__ qklo,
               const unsigned* __restrict__ vtx,
               unsigned short* __restrict__ ohi, unsigned short* __restrict__ olo)
{
    __shared__ __align__(16) unsigned short SM[24064];
    #define KH(r,d) SM[(r)*136 + (d)]
    #define KL(r,d) SM[4352 + (r)*136 + (d)]
    #define VH(d,k) SM[8704 + (d)*40 + (k)]
    #define VL(d,k) SM[13824 + (d)*40 + (k)]
    #define PH(r,k) SM[18944 + (r)*40 + (k)]
    #define PL(r,k) SM[21504 + (r)*40 + (k)]
    #define OS(r,d) SM[(r)*136 + (d)]

    const int t = threadIdx.x;
    const int lane = t & 63, w = t >> 6;
    const int id = xcd_swz(blockIdx.x, gridDim.x);
    const int qt = id % 9;
    const int hb = id / 9;
    const int h = hb & 3, b = hb >> 2;
    const int q0 = qt * AQT;
    const int c = lane & 15, g = lane >> 4;
    const float SCALE = 0.08838834764831845f;

    short8v qh[4], ql[4];
    {
        int qrow = b * LC + q0 + w * 16 + c;
        if (qrow > MROWS - 1) qrow = MROWS - 1;
        const unsigned short* bh_ = qkhi + (size_t)qrow * 1024 + h * DH;
        const unsigned short* bl_ = qklo + (size_t)qrow * 1024 + h * DH;
        #pragma unroll
        for (int ks = 0; ks < 4; ks++) {
            qh[ks] = *(const short8v*)(bh_ + ks * 32 + g * 8);
            ql[ks] = *(const short8v*)(bl_ + ks * 32 + g * 8);
        }
    }

    float m_r[4], l_r[4];
    #pragma unroll
    for (int r = 0; r < 4; r++) { m_r[r] = -INFINITY; l_r[r] = 0.f; }
    f32x4 acc_o[8];
    #pragma unroll
    for (int n = 0; n < 8; n++) { acc_o[n][0]=0.f; acc_o[n][1]=0.f; acc_o[n][2]=0.f; acc_o[n][3]=0.f; }

    const int skr = t >> 3, skd = (t & 7) * 16;
    const int svd = t >> 1, svk = (t & 1) * 16;
    const unsigned short* kbase  = qkhi + 512 + h * DH + skd;
    const unsigned short* kbasel = qklo + 512 + h * DH + skd;
    const unsigned* vbase = vtx + ((size_t)((b * HH + h) * DH + svd)) * VTSTRIDE + svk;

    short8v rk0, rk1, rl0, rl1;
    uint4 rv0, rv1, rv2, rv3;
    {
        int krow = b * LC + skr; if (krow > MROWS - 1) krow = MROWS - 1;
        const unsigned short* kb  = kbase  + (size_t)krow * 1024;
        const unsigned short* kbl = kbasel + (size_t)krow * 1024;
        rk0 = *(const short8v*)kb;  rk1 = *(const short8v*)(kb + 8);
        rl0 = *(const short8v*)kbl; rl1 = *(const short8v*)(kbl + 8);
        rv0 = *(const uint4*)(vbase);
        rv1 = *(const uint4*)(vbase + 4);
        rv2 = *(const uint4*)(vbase + 8);
        rv3 = *(const uint4*)(vbase + 12);
    }

    for (int kt = 0; kt < NKT2; kt++) {
        __builtin_amdgcn_s_barrier();
        *(short8v*)&KH(skr, skd)     = rk0;
        *(short8v*)&KH(skr, skd + 8) = rk1;
        *(short8v*)&KL(skr, skd)     = rl0;
        *(short8v*)&KL(skr, skd + 8) = rl1;
        {
            uint4 hA, hB, lA, lB;
            hA.x = (rv0.x & 0xffffu) | (rv0.y << 16);
            hA.y = (rv0.z & 0xffffu) | (rv0.w << 16);
            hA.z = (rv1.x & 0xffffu) | (rv1.y << 16);
            hA.w = (rv1.z & 0xffffu) | (rv1.w << 16);
            hB.x = (rv2.x & 0xffffu) | (rv2.y << 16);
            hB.y = (rv2.z & 0xffffu) | (rv2.w << 16);
            hB.z = (rv3.x & 0xffffu) | (rv3.y << 16);
            hB.w = (rv3.z & 0xffffu) | (rv3.w << 16);
            lA.x = (rv0.x >> 16) | (rv0.y & 0xffff0000u);
            lA.y = (rv0.z >> 16) | (rv0.w & 0xffff0000u);
            lA.z = (rv1.x >> 16) | (rv1.y & 0xffff0000u);
            lA.w = (rv1.z >> 16) | (rv1.w & 0xffff0000u);
            lB.x = (rv2.x >> 16) | (rv2.y & 0xffff0000u);
            lB.y = (rv2.z >> 16) | (rv2.w & 0xffff0000u);
            lB.z = (rv3.x >> 16) | (rv3.y & 0xffff0000u);
            lB.w = (rv3.z >> 16) | (rv3.w & 0xffff0000u);
            *(uint4*)&VH(svd, svk)     = hA;
            *(uint4*)&VH(svd, svk + 8) = hB;
            *(uint4*)&VL(svd, svk)     = lA;
            *(uint4*)&VL(svd, svk + 8) = lB;
        }
        if (kt + 1 < NKT2) {
            int krow = b * LC + (kt + 1) * AKT + skr;
            if (krow > MROWS - 1) krow = MROWS - 1;
            const unsigned short* kb  = kbase  + (size_t)krow * 1024;
            const unsigned short* kbl = kbasel + (size_t)krow * 1024;
            rk0 = *(const short8v*)kb;  rk1 = *(const short8v*)(kb + 8);
            rl0 = *(const short8v*)kbl; rl1 = *(const short8v*)(kbl + 8);
            const unsigned* vb = vbase + (kt + 1) * AKT;
            rv0 = *(const uint4*)(vb);
            rv1 = *(const uint4*)(vb + 4);
            rv2 = *(const uint4*)(vb + 8);
            rv3 = *(const uint4*)(vb + 12);
        }
        asm volatile("s_waitcnt lgkmcnt(0)" ::: "memory");
        __builtin_amdgcn_s_barrier();
        __builtin_amdgcn_sched_barrier(0);

        f32x4 s[2];
        s[0][0]=s[0][1]=s[0][2]=s[0][3]=0.f;
        s[1][0]=s[1][1]=s[1][2]=s[1][3]=0.f;
        __builtin_amdgcn_s_setprio(1);
        #pragma unroll
        for (int n = 0; n < 2; n++) {
            #pragma unroll
            for (int ks = 0; ks < 4; ks++) {
                short8v kh = *(const short8v*)&KH(n * 16 + c, ks * 32 + g * 8);
                short8v kl = *(const short8v*)&KL(n * 16 + c, ks * 32 + g * 8);
                s[n] = MFMA16(qh[ks], kh, s[n]);
                s[n] = MFMA16(ql[ks], kh, s[n]);
                s[n] = MFMA16(qh[ks], kl, s[n]);
            }
        }
        __builtin_amdgcn_s_setprio(0);

        #pragma unroll
        for (int n = 0; n < 2; n++) {
            bool oob = (kt * 32 + n * 16 + c) >= LC;
            #pragma unroll
            for (int r = 0; r < 4; r++) {
                float sv = s[n][r] * SCALE;
                s[n][r] = oob ? -INFINITY : sv;
            }
        }

        float alpha[4], p0v[4], p1v[4];
        #pragma unroll
        for (int r = 0; r < 4; r++) {
            float rm = fmaxf(s[0][r], s[1][r]);
            #pragma unroll
            for (int off = 1; off < 16; off <<= 1) rm = fmaxf(rm, __shfl_xor(rm, off));
            float mn = fmaxf(m_r[r], rm);
            float p0 = expf(s[0][r] - mn);
            float p1 = expf(s[1][r] - mn);
            float ts = p0 + p1;
            #pragma unroll
            for (int off = 1; off < 16; off <<= 1) ts += __shfl_xor(ts, off);
            float al = expf(m_r[r] - mn);
            m_r[r] = mn;
            l_r[r] = al * l_r[r] + ts;
            alpha[r] = al;
            p0v[r] = p0; p1v[r] = p1;
        }

        #pragma unroll
        for (int n = 0; n < 8; n++)
            #pragma unroll
            for (int r = 0; r < 4; r++) acc_o[n][r] *= alpha[r];

        #pragma unroll
        for (int r = 0; r < 4; r++) {
            unsigned short ph, pl;
            split_bf(p0v[r], ph, pl);
            PH(w * 16 + g * 4 + r, c) = ph;
            PL(w * 16 + g * 4 + r, c) = pl;
            split_bf(p1v[r], ph, pl);
            PH(w * 16 + g * 4 + r, 16 + c) = ph;
            PL(w * 16 + g * 4 + r, 16 + c) = pl;
        }
        short8v pah = *(const short8v*)&PH(w * 16 + c, g * 8);
        short8v pal = *(const short8v*)&PL(w * 16 + c, g * 8);
        __builtin_amdgcn_s_setprio(1);
        #pragma unroll
        for (int n = 0; n < 8; n++) {
            short8v vh = *(const short8v*)&VH(n * 16 + c, g * 8);
            short8v vl = *(const short8v*)&VL(n * 16 + c, g * 8);
            acc_o[n] = MFMA16(pah, vh, acc_o[n]);
            acc_o[n] = MFMA16(pal, vh, acc_o[n]);
            acc_o[n] = MFMA16(pah, vl, acc_o[n]);
        }
        __builtin_amdgcn_s_setprio(0);
    }

    float inv[4];
    #pragma unroll
    for (int r = 0; r < 4; r++) inv[r] = 1.0f / l_r[r];

    const int orow = t >> 2, oc0 = (t & 3) * 32;
    #pragma unroll
    for (int pass = 0; pass < 2; pass++) {
        __syncthreads();
        #pragma unroll
        for (int n = 0; n < 8; n++)
            #pragma unroll
            for (int r = 0; r < 4; r++) {
                float v = acc_o[n][r] * inv[r];
                unsigned short hv, lv;
                split_bf(v, hv, lv);
                OS(w * 16 + g * 4 + r, n * 16 + c) = pass ? lv : hv;
            }
        __syncthreads();
        int grow = q0 + orow;
        if (grow < LC) {
            unsigned short* dst = (pass ? olo : ohi) + ((size_t)(b * LC + grow)) * DD + h * DH + oc0;
            #pragma unroll
            for (int u = 0; u < 4; u++)
                *(short8v*)(dst + u * 8) = *(const short8v*)&OS(orow, oc0 + u * 8);
        }
    }
    #undef KH
    #undef KL
    #undef VH
    #undef VL
    #undef PH
    #undef PL
    #undef OS
}

// ---------------- LayerNorm over 512 (wave per row) ----------------
__global__ __launch_bounds__(256)
void ln512(const float* __restrict__ X, const float* __restrict__ g,
           const float* __restrict__ bb, float* __restrict__ Y,
           unsigned short* __restrict__ Yhi, unsigned short* __restrict__ Ylo)
{
    int row = blockIdx.x * 4 + (threadIdx.x >> 6);
    int lane = threadIdx.x & 63;
    const float* x = X + (size_t)row * DD + lane * 8;
    float4 v0 = *(const float4*)x;
    float4 v1 = *(const float4*)(x + 4);
    float vv[8] = {v0.x,v0.y,v0.z,v0.w,v1.x,v1.y,v1.z,v1.w};
    float s = 0.f;
    #pragma unroll
    for (int i = 0; i < 8; i++) s += vv[i];
    #pragma unroll
    for (int off = 1; off < 64; off <<= 1) s += __shfl_xor(s, off);
    float mean = s * (1.0f / 512.0f);
    float d[8], s2 = 0.f;
    #pragma unroll
    for (int i = 0; i < 8; i++) { d[i] = vv[i] - mean; s2 += d[i] * d[i]; }
    #pragma unroll
    for (int off = 1; off < 64; off <<= 1) s2 += __shfl_xor(s2, off);
    float var = s2 * (1.0f / 512.0f);
    float rstd = 1.0f / sqrtf(var + 1e-5f);
    float4 g0 = *(const float4*)(g + lane * 8);
    float4 g1 = *(const float4*)(g + lane * 8 + 4);
    float4 b0 = *(const float4*)(bb + lane * 8);
    float4 b1 = *(const float4*)(bb + lane * 8 + 4);
    float gg[8] = {g0.x,g0.y,g0.z,g0.w,g1.x,g1.y,g1.z,g1.w};
    float bv[8] = {b0.x,b0.y,b0.z,b0.w,b1.x,b1.y,b1.z,b1.w};
    float ov[8];
    unsigned short hs[8], ls[8];
    #pragma unroll
    for (int i = 0; i < 8; i++) {
        ov[i] = d[i] * rstd * gg[i] + bv[i];
        split_bf(ov[i], hs[i], ls[i]);
    }
    size_t o = (size_t)row * DD + lane * 8;
    *(float4*)(Y + o)     = make_float4(ov[0], ov[1], ov[2], ov[3]);
    *(float4*)(Y + o + 4) = make_float4(ov[4], ov[5], ov[6], ov[7]);
    uint4 hv, lv;
    hv.x = (unsigned)hs[0] | ((unsigned)hs[1] << 16);
    hv.y = (unsigned)hs[2] | ((unsigned)hs[3] << 16);
    hv.z = (unsigned)hs[4] | ((unsigned)hs[5] << 16);
    hv.w = (unsigned)hs[6] | ((unsigned)hs[7] << 16);
    lv.x = (unsigned)ls[0] | ((unsigned)ls[1] << 16);
    lv.y = (unsigned)ls[2] | ((unsigned)ls[3] << 16);
    lv.z = (unsigned)ls[4] | ((unsigned)ls[5] << 16);
    lv.w = (unsigned)ls[6] | ((unsigned)ls[7] << 16);
    *(uint4*)(Yhi + o) = hv;
    *(uint4*)(Ylo + o) = lv;
}

// ---------------- mean over L (two-pass) ----------------
__global__ __launch_bounds__(128)
void mean_part(const float* __restrict__ query, float* __restrict__ part)
{
    int b = blockIdx.x, ch = blockIdx.y, t = threadIdx.x;
    const float* base = query + ((size_t)b * LQ + ch * 64) * DD + t * 4;
    float ax = 0.f, ay = 0.f, az = 0.f, aw = 0.f;
    for (int l = 0; l < 64; l++) {
        float4 v = *(const float4*)(base + (size_t)l * DD);
        ax += v.x; ay += v.y; az += v.z; aw += v.w;
    }
    *(float4*)(part + ((size_t)(b * 8 + ch)) * DD + t * 4) = make_float4(ax, ay, az, aw);
}

__global__ __launch_bounds__(128)
void mean_fin(const float* __restrict__ part, float* __restrict__ xm)
{
    int b = blockIdx.x, t = threadIdx.x;
    float ax = 0.f, ay = 0.f, az = 0.f, aw = 0.f;
    #pragma unroll
    for (int ch = 0; ch < 8; ch++) {
        float4 v = *(const float4*)(part + ((size_t)(b * 8 + ch)) * DD + t * 4);
        ax += v.x; ay += v.y; az += v.z; aw += v.w;
    }
    *(float4*)(xm + (size_t)b * DD + t * 4) =
        make_float4(ax * (1.f/512.f), ay * (1.f/512.f), az * (1.f/512.f), aw * (1.f/512.f));
}

static __device__ __forceinline__ float block128_sum(float x, float* red, int t) {
    #pragma unroll
    for (int off = 1; off < 64; off <<= 1) x += __shfl_xor(x, off);
    if ((t & 63) == 0) red[t >> 6] = x;
    __syncthreads();
    float r = red[0] + red[1];
    __syncthreads();
    return r;
}

// ---------------- proj + LN -> q_repr ----------------
__global__ __launch_bounds__(128)
void proj_ln(const float* __restrict__ h, const float* __restrict__ pW, const float* __restrict__ pb,
             const float* __restrict__ pg, const float* __restrict__ pbb, float* __restrict__ q_repr)
{
    __shared__ float xs[DD];
    __shared__ float red[2];
    int b = blockIdx.x, t = threadIdx.x;
    *(float4*)&xs[t * 4] = *(const float4*)(h + (size_t)(b * LC) * DD + t * 4);
    __syncthreads();
    const float* w = pW + (size_t)t * DD;
    float acc = pb[t];
    for (int k = 0; k < DD; k += 4) {
        float4 a = *(const float4*)&xs[k];
        float4 ww = *(const float4*)(w + k);
        acc += a.x * ww.x + a.y * ww.y + a.z * ww.z + a.w * ww.w;
    }
    float mean = block128_sum(acc, red, t) * (1.f / 128.f);
    float dx = acc - mean;
    float var = block128_sum(dx * dx, red, t) * (1.f / 128.f);
    float rstd = 1.0f / sqrtf(var + 1e-5f);
    q_repr[(size_t)b * DRr + t] = dx * rstd * pg[t] + pbb[t];
}

// ---------------- value encoder (fused) -> q_val ----------------
__global__ __launch_bounds__(128)
void venc(const float* __restrict__ xm, const float* __restrict__ vW1, const float* __restrict__ vb1,
          const float* __restrict__ vg, const float* __restrict__ vb,
          const float* __restrict__ vW2, const float* __restrict__ vb2,
          float* __restrict__ q_val)
{
    __shared__ float xs[DD];
    __shared__ float hg[DRr];
    __shared__ float red[2];
    int b = blockIdx.x, t = threadIdx.x;
    *(float4*)&xs[t * 4] = *(const float4*)(xm + (size_t)b * DD + t * 4);
    __syncthreads();
    const float* w = vW1 + (size_t)t * DD;
    float acc = vb1[t];
    for (int k = 0; k < DD; k += 4) {
        float4 a = *(const float4*)&xs[k];
        float4 ww = *(const float4*)(w + k);
        acc += a.x * ww.x + a.y * ww.y + a.z * ww.z + a.w * ww.w;
    }
    float mean = block128_sum(acc, red, t) * (1.f / 128.f);
    float dx = acc - mean;
    float var = block128_sum(dx * dx, red, t) * (1.f / 128.f);
    float rstd = 1.0f / sqrtf(var + 1e-5f);
    float hn = dx * rstd * vg[t] + vb[t];
    hg[t] = gelu_exact(hn);
    __syncthreads();
    const float* w2 = vW2 + (size_t)t * DRr;
    float acc2 = vb2[t];
    for (int k = 0; k < DRr; k += 4) {
        float4 a = *(const float4*)&hg[k];
        float4 ww = *(const float4*)(w2 + k);
        acc2 += a.x * ww.x + a.y * ww.y + a.z * ww.z + a.w * ww.w;
    }
    q_val[(size_t)b * DRr + t] = acc2;
}

// ---------------- combine ----------------
__global__ void combine_qk(const float* __restrict__ qr, const float* __restrict__ qv,
                           const float* __restrict__ swp, float* __restrict__ qk)
{
    int i = blockIdx.x * blockDim.x + threadIdx.x;
    if (i < B_ * DRr) {
        float sw = swp[0];
        qk[i] = sw * qr[i] + (1.f - sw) * qv[i];
    }
}

// ---------------- fused sim + top-k (jax tie semantics) ----------------
static __device__ __forceinline__ void topk_insert(float* v, int* id, float x, int n) {
    bool better = (x > v[TOPK - 1]) || (x == v[TOPK - 1] && n < id[TOPK - 1]);
    if (better) {
        v[TOPK - 1] = x; id[TOPK - 1] = n;
        #pragma unroll
        for (int k = TOPK - 1; k > 0; k--) {
            bool sw = (v[k] > v[k - 1]) || (v[k] == v[k - 1] && id[k] < id[k - 1]);
            if (!sw) break;
            float tv = v[k]; v[k] = v[k - 1]; v[k - 1] = tv;
            int ti = id[k]; id[k] = id[k - 1]; id[k - 1] = ti;
        }
    }
}

__global__ __launch_bounds__(256)
void sim_topk(const float* __restrict__ qk, const float* __restrict__ mkeys,
              int* __restrict__ topidx, float* __restrict__ wout)
{
    __shared__ float qs[DRr];
    __shared__ float sv[256][TOPK];
    __shared__ int   si[256][TOPK];
    int b = blockIdx.x, t = threadIdx.x;
    if (t < DRr) qs[t] = qk[(size_t)b * DRr + t];
    __syncthreads();
    float qn = 0.f;
    #pragma unroll 8
    for (int i = 0; i < DRr; i++) qn += qs[i] * qs[i];

    float v[TOPK]; int id[TOPK];
    #pragma unroll
    for (int k = 0; k < TOPK; k++) { v[k] = -INFINITY; id[k] = 0x7fffffff; }
    for (int n = t; n < NKEYS; n += 256) {
        const float* kr = mkeys + (size_t)n * DRr;
        float dot = 0.f, kn = 0.f;
        #pragma unroll 8
        for (int i = 0; i < DRr; i += 4) {
            float4 kv = *(const float4*)(kr + i);
            dot += qs[i] * kv.x + qs[i + 1] * kv.y + qs[i + 2] * kv.z + qs[i + 3] * kv.w;
            kn  += kv.x * kv.x + kv.y * kv.y + kv.z * kv.z + kv.w * kv.w;
        }
        float d = qn - 2.f * dot + kn;
        topk_insert(v, id, -d / 0.1f, n);
    }
    #pragma unroll
    for (int k = 0; k < TOPK; k++) { sv[t][k] = v[k]; si[t][k] = id[k]; }
    for (int strd = 128; strd >= 1; strd >>= 1) {
        __syncthreads();
        if (t < strd) {
            #pragma unroll
            for (int k = 0; k < TOPK; k++) topk_insert(v, id, sv[t + strd][k], si[t + strd][k]);
            #pragma unroll
            for (int k = 0; k < TOPK; k++) { sv[t][k] = v[k]; si[t][k] = id[k]; }
        }
    }
    if (t == 0) {
        float m = v[0];
        float e[TOPK]; float sum = 0.f;
        #pragma unroll
        for (int k = 0; k < TOPK; k++) { e[k] = expf(v[k] - m); sum += e[k]; }
        #pragma unroll
        for (int k = 0; k < TOPK; k++) {
            wout[(size_t)b * TOPK + k] = e[k] / sum;
            topidx[b * TOPK + k] = id[k];
        }
    }
}

// ---------------- gather ----------------
__global__ __launch_bounds__(128)
void gather_kernel(const float* __restrict__ mv, const int* __restrict__ topidx, float* __restrict__ out)
{
    int blk = blockIdx.x;
    int b = blk / (TOPK * PP);
    int rem = blk - b * (TOPK * PP);
    int k = rem / PP;
    int p = rem - k * PP;
    int idx = topidx[b * TOPK + k];
    const float4* src = (const float4*)(mv + ((size_t)idx * PP + p) * DD);
    float4* dst = (float4*)(out + (size_t)blk * DD);
    dst[threadIdx.x] = src[threadIdx.x];
}

// ---------------- launch ----------------
extern "C" void kernel_launch(void* const* d_in, const int* in_sizes, int n_in,
                              void* d_out, int out_size, void* d_ws, size_t ws_size,
                              hipStream_t stream) {
    const float* query = (const float*)d_in[0];
    const float* mkeys = (const float*)d_in[1];
    const float* mvals = (const float*)d_in[2];
    const float* cls   = (const float*)d_in[3];
    const float* Wqkv  = (const float*)d_in[4];
    const float* bqkv  = (const float*)d_in[5];
    const float* Wo    = (const float*)d_in[6];
    const float* bo    = (const float*)d_in[7];
    const float* ln1g  = (const float*)d_in[8];
    const float* ln1b  = (const float*)d_in[9];
    const float* W1    = (const float*)d_in[10];
    const float* b1    = (const float*)d_in[11];
    const float* W2    = (const float*)d_in[12];
    const float* b2    = (const float*)d_in[13];
    const float* ln2g  = (const float*)d_in[14];
    const float* ln2b  = (const float*)d_in[15];
    const float* pW    = (const float*)d_in[16];
    const float* pb    = (const float*)d_in[17];
    const float* pg    = (const float*)d_in[18];
    const float* pbb   = (const float*)d_in[19];
    const float* vW1   = (const float*)d_in[20];
    const float* vb1   = (const float*)d_in[21];
    const float* vg    = (const float*)d_in[22];
    const float* vb    = (const float*)d_in[23];
    const float* vW2   = (const float*)d_in[24];
    const float* vb2   = (const float*)d_in[25];
    const float* swp   = (const float*)d_in[26];
    float* out = (float*)d_out;

    // ---- workspace layout ----
    float* ws    = (float*)d_ws;
    float* h     = ws;
    float* preln = h + (size_t)MROWS * DD;
    unsigned short* h_hi  = (unsigned short*)(preln + (size_t)MROWS * DD);
    unsigned short* h_lo  = h_hi  + (size_t)MROWS * DD;
    unsigned short* mid_hi = h_lo + (size_t)MROWS * DD;
    unsigned short* mid_lo = mid_hi + (size_t)MROWS * 1024;
    unsigned short* qkhi  = mid_lo + (size_t)MROWS * 1024;
    unsigned short* qklo  = qkhi  + (size_t)MROWS * 1024;
    unsigned* vtx         = (unsigned*)(qklo + (size_t)MROWS * 1024);
    unsigned short* wq_hi = (unsigned short*)(vtx + (size_t)32768 * VTSTRIDE);
    unsigned short* wq_lo = wq_hi + (size_t)2 * 1536 * DD;
    unsigned short* wo_hi = wq_lo + (size_t)2 * 1536 * DD;
    unsigned short* wo_lo = wo_hi + (size_t)2 * DD * DD;
    unsigned short* w1_hi = wo_lo + (size_t)2 * DD * DD;
    unsigned short* w1_lo = w1_hi + (size_t)2 * 1024 * DD;
    unsigned short* w2_hi = w1_lo + (size_t)2 * 1024 * DD;
    unsigned short* w2_lo = w2_hi + (size_t)2 * DD * 1024;
    float* xm   = (float*)(w2_lo + (size_t)2 * DD * 1024);
    float* qval = xm   + (size_t)B_ * DD;
    float* qrep = qval + (size_t)B_ * DRr;
    float* qkc  = qrep + (size_t)B_ * DRr;
    int*   tidx = (int*)(qkc + (size_t)B_ * DRr);
    float* mpart = (float*)(tidx + 512);
    (void)ws_size; (void)in_sizes; (void)n_in; (void)out_size;

    // ---- weight splits ----
    {
        int n4;
        n4 = 2 * 1536 * DD / 4;
        split_kernel<<<(n4 + 255) / 256, 256, 0, stream>>>(Wqkv, wq_hi, wq_lo, n4);
        n4 = 2 * DD * DD / 4;
        split_kernel<<<(n4 + 255) / 256, 256, 0, stream>>>(Wo, wo_hi, wo_lo, n4);
        n4 = 2 * 1024 * DD / 4;
        split_kernel<<<(n4 + 255) / 256, 256, 0, stream>>>(W1, w1_hi, w1_lo, n4);
        n4 = 2 * DD * 1024 / 4;
        split_kernel<<<(n4 + 255) / 256, 256, 0, stream>>>(W2, w2_hi, w2_lo, n4);
    }

    concat_cls<<<MROWS / 4, 256, 0, stream>>>(query, cls, h, h_hi, h_lo);

    for (int l = 0; l < 2; l++) {
        const unsigned short* wqh = wq_hi + (size_t)l * 1536 * DD;
        const unsigned short* wql = wq_lo + (size_t)l * 1536 * DD;
        const unsigned short* woh = wo_hi + (size_t)l * DD * DD;
        const unsigned short* wol = wo_lo + (size_t)l * DD * DD;
        const unsigned short* w1h = w1_hi + (size_t)l * 1024 * DD;
        const unsigned short* w1l = w1_lo + (size_t)l * 1024 * DD;
        const unsigned short* w2h = w2_hi + (size_t)l * DD * 1024;
        const unsigned short* w2l = w2_lo + (size_t)l * DD * 1024;
        const float* bq  = bqkv + (size_t)l * 1536;
        const float* bol = bo   + (size_t)l * DD;
        const float* g1  = ln1g + (size_t)l * DD;
        const float* be1 = ln1b + (size_t)l * DD;
        const float* b1l = b1   + (size_t)l * 1024;
        const float* b2l = b2   + (size_t)l * DD;
        const float* g2  = ln2g + (size_t)l * DD;
        const float* be2 = ln2b + (size_t)l * DD;

        // QKV -> qk splits + transposed interleaved V
        gemm3<3><<<257 * 12, 256, 0, stream>>>(h_hi, h_lo, wqh, wql, bq, nullptr,
                                               nullptr, qkhi, qklo, vtx,
                                               MROWS, 1536, DD, 12);
        // MFMA attention -> h_hi/h_lo (attn-out splits)
        attn_mfma<<<9 * HH * B_, 256, 0, stream>>>(qkhi, qklo, vtx, h_hi, h_lo);
        // Wo + residual -> preln fp32
        gemm3<1><<<257 * 4, 256, 0, stream>>>(h_hi, h_lo, woh, wol, bol, h,
                                              preln, nullptr, nullptr, nullptr,
                                              MROWS, DD, DD, 4);
        ln512<<<MROWS / 4, 256, 0, stream>>>(preln, g1, be1, h, h_hi, h_lo);
        // FFN1 + gelu -> mid splits
        gemm3<2><<<257 * 8, 256, 0, stream>>>(h_hi, h_lo, w1h, w1l, b1l, nullptr,
                                              nullptr, mid_hi, mid_lo, nullptr,
                                              MROWS, 1024, DD, 8);
        // FFN2 + residual -> preln fp32
        gemm3<1><<<257 * 4, 256, 0, stream>>>(mid_hi, mid_lo, w2h, w2l, b2l, h,
                                              preln, nullptr, nullptr, nullptr,
                                              MROWS, DD, 1024, 4);
        ln512<<<MROWS / 4, 256, 0, stream>>>(preln, g2, be2, h, h_hi, h_lo);
    }

    proj_ln<<<B_, 128, 0, stream>>>(h, pW, pb, pg, pbb, qrep);
    mean_part<<<dim3(B_, 8), 128, 0, stream>>>(query, mpart);
    mean_fin<<<B_, 128, 0, stream>>>(mpart, xm);
    venc<<<B_, 128, 0, stream>>>(xm, vW1, vb1, vg, vb, vW2, vb2, qval);
    combine_qk<<<(B_ * DRr + 255) / 256, 256, 0, stream>>>(qrep, qval, swp, qkc);
    sim_topk<<<B_, 256, 0, stream>>>(qkc, mkeys, tidx, out + (size_t)B_ * TOPK * PP * DD);
    gather_kernel<<<B_ * TOPK * PP, 128, 0, stream>>>(mvals, tidx, out);
}

// Round 13
// 2421.254 us; speedup vs baseline: 1.0586x; 1.0586x over previous
//
#include <hip/hip_runtime.h>
#include <math.h>

// Problem dims
#define B_    64
#define LQ    512
#define LC    513          // with CLS
#define DD    512
#define HH    4
#define DH    128
#define DRr   128
#define NKEYS 10000
#define PP    96
#define TOPK  5
#define MROWS (B_*LC)      // 32832
#define VTSTRIDE 544       // padded LC for transposed V (multiple of 16)

typedef __attribute__((ext_vector_type(8))) short short8v;
typedef __attribute__((ext_vector_type(4))) float f32x4;
typedef __attribute__((ext_vector_type(16))) float f32x16;

static __device__ __forceinline__ float gelu_exact(float x) {
    return 0.5f * x * (1.0f + erff(x * 0.70710678118654752440f));
}

static __device__ __forceinline__ unsigned short f2bf(float x) {
    union { float f; unsigned u; } v; v.f = x;
    unsigned r = v.u + 0x7fff + ((v.u >> 16) & 1);
    return (unsigned short)(r >> 16);
}
static __device__ __forceinline__ float bf2f(unsigned short h) {
    union { float f; unsigned u; } v; v.u = ((unsigned)h) << 16;
    return v.f;
}
static __device__ __forceinline__ void split_bf(float x, unsigned short& hi, unsigned short& lo) {
    hi = f2bf(x);
    lo = f2bf(x - bf2f(hi));
}

// bijective XCD-aware swizzle (m204)
static __device__ __forceinline__ int xcd_swz(int orig, int nwg) {
    int xcd = orig & 7;
    int lid = orig >> 3;
    int q = nwg >> 3, r = nwg & 7;
    int base = (xcd < r) ? xcd * (q + 1) : r * (q + 1) + (xcd - r) * q;
    return base + lid;
}

// async global->LDS, 16B per lane. LDS dest linear: base + lane*16.
static __device__ __forceinline__ void gload16(const unsigned short* g, unsigned short* l) {
    __builtin_amdgcn_global_load_lds(
        (const __attribute__((address_space(1))) unsigned*)g,
        (__attribute__((address_space(3))) unsigned*)l, 16, 0, 0);
}

// ---------------- generic fp32 -> (hi,lo) bf16 split ----------------
__global__ __launch_bounds__(256)
void split_kernel(const float* __restrict__ x, unsigned short* __restrict__ hi,
                  unsigned short* __restrict__ lo, int n4)
{
    int i = blockIdx.x * blockDim.x + threadIdx.x;
    if (i >= n4) return;
    float4 v = ((const float4*)x)[i];
    unsigned short h0,h1,h2,h3,l0,l1,l2,l3;
    split_bf(v.x,h0,l0); split_bf(v.y,h1,l1); split_bf(v.z,h2,l2); split_bf(v.w,h3,l3);
    ((uint2*)hi)[i] = make_uint2((unsigned)h0 | ((unsigned)h1 << 16), (unsigned)h2 | ((unsigned)h3 << 16));
    ((uint2*)lo)[i] = make_uint2((unsigned)l0 | ((unsigned)l1 << 16), (unsigned)l2 | ((unsigned)l3 << 16));
}

// ---------------- concat cls + query -> h (wave per row) ----------------
__global__ __launch_bounds__(256)
void concat_cls(const float* __restrict__ query, const float* __restrict__ cls,
                float* __restrict__ h, unsigned short* __restrict__ h_hi,
                unsigned short* __restrict__ h_lo)
{
    int row = blockIdx.x * 4 + (threadIdx.x >> 6);
    int lane = threadIdx.x & 63;
    int b = row / LC, r = row - b * LC;
    const float* src = (r == 0) ? (cls + lane * 8)
                                : (query + ((size_t)b * LQ + (r - 1)) * DD + lane * 8);
    float4 v0 = *(const float4*)src;
    float4 v1 = *(const float4*)(src + 4);
    size_t o = (size_t)row * DD + lane * 8;
    *(float4*)(h + o) = v0;
    *(float4*)(h + o + 4) = v1;
    float vv[8] = {v0.x,v0.y,v0.z,v0.w,v1.x,v1.y,v1.z,v1.w};
    unsigned short hs[8], ls[8];
    #pragma unroll
    for (int i = 0; i < 8; i++) split_bf(vv[i], hs[i], ls[i]);
    uint4 hv, lv;
    hv.x = (unsigned)hs[0] | ((unsigned)hs[1] << 16);
    hv.y = (unsigned)hs[2] | ((unsigned)hs[3] << 16);
    hv.z = (unsigned)hs[4] | ((unsigned)hs[5] << 16);
    hv.w = (unsigned)hs[6] | ((unsigned)hs[7] << 16);
    lv.x = (unsigned)ls[0] | ((unsigned)ls[1] << 16);
    lv.y = (unsigned)ls[2] | ((unsigned)ls[3] << 16);
    lv.z = (unsigned)ls[4] | ((unsigned)ls[5] << 16);
    lv.w = (unsigned)ls[6] | ((unsigned)ls[7] << 16);
    *(uint4*)(h_hi + o) = hv;
    *(uint4*)(h_lo + o) = lv;
}

// ---------------- split-bf16 MFMA GEMM (32x32x16), round-6 structure ------
// MODE 0: C fp32 = acc + bias
// MODE 1: C fp32 = acc + bias + res
// MODE 2: (hi,lo) bf16 = gelu(acc + bias)
// MODE 3: QKV: col0<1024 -> qk hi/lo; col0>=1024 -> transposed V (interleaved)
#define BM 128
#define BN 128
#define BK 32

#define MFMA32(a, b, c) __builtin_amdgcn_mfma_f32_32x32x16_bf16(a, b, c, 0, 0, 0)

template<int MODE>
__global__ __launch_bounds__(256)
void gemm3(const unsigned short* __restrict__ Ahi, const unsigned short* __restrict__ Alo,
           const unsigned short* __restrict__ Whi, const unsigned short* __restrict__ Wlo,
           const float* __restrict__ bias, const float* __restrict__ res,
           float* __restrict__ Cf, unsigned short* __restrict__ Chi,
           unsigned short* __restrict__ Clo, unsigned* __restrict__ Vix,
           int M, int N, int K, int NBN)
{
    __shared__ __align__(16) unsigned short POOL[16384];   // 32KB

    const int t = threadIdx.x;
    const int lane = t & 63, w = t >> 6;
    const int wr = w >> 1, wc = w & 1;
    const int wg = xcd_swz(blockIdx.x, gridDim.x);
    const int bm = wg / NBN, bn = wg - bm * NBN;
    const int row0 = bm * BM, col0 = bn * BN;

    // staging coords: thread t covers (rows t>>2 and t>>2+64, 16B block t&3)
    const int srow = t >> 2;
    const int sg   = t & 3;
    const int glog = sg ^ (srow & 3);
    int ar0 = row0 + srow;      if (ar0 >= M) ar0 = M - 1;
    int ar1 = row0 + srow + 64; if (ar1 >= M) ar1 = M - 1;
    const size_t aoff0 = (size_t)ar0 * K + glog * 8;
    const size_t aoff1 = (size_t)ar1 * K + glog * 8;
    const size_t boff0 = (size_t)(col0 + srow) * K + glog * 8;
    const size_t boff1 = (size_t)(col0 + srow + 64) * K + glog * 8;
    const int ldso0 = t * 8;
    const int ldso1 = t * 8 + 2048;

    f32x16 acc[2][2];
    #pragma unroll
    for (int m = 0; m < 2; m++)
        #pragma unroll
        for (int n = 0; n < 2; n++)
            #pragma unroll
            for (int i = 0; i < 16; i++) acc[m][n][i] = 0.f;

    const int cl = lane & 31;
    const int kg = lane >> 5;
    const int cl3 = cl & 3;

    unsigned short* LAh = POOL;
    unsigned short* LAl = POOL + 4096;
    unsigned short* LBh = POOL + 8192;
    unsigned short* LBl = POOL + 12288;

    const int KT = K / BK;
    for (int kt = 0; kt < KT; kt++) {
        const int k0 = kt * BK;
        __syncthreads();
        gload16(Ahi + aoff0 + k0, &LAh[ldso0]);
        gload16(Ahi + aoff1 + k0, &LAh[ldso1]);
        gload16(Alo + aoff0 + k0, &LAl[ldso0]);
        gload16(Alo + aoff1 + k0, &LAl[ldso1]);
        gload16(Whi + boff0 + k0, &LBh[ldso0]);
        gload16(Whi + boff1 + k0, &LBh[ldso1]);
        gload16(Wlo + boff0 + k0, &LBl[ldso0]);
        gload16(Wlo + boff1 + k0, &LBl[ldso1]);
        __syncthreads();

        #pragma unroll
        for (int ks = 0; ks < 2; ks++) {
            const int blkswz = ((ks * 2 + kg) ^ cl3) * 8;
            short8v ah[2], al[2], bh[2], bl[2];
            #pragma unroll
            for (int m = 0; m < 2; m++) {
                int off = (wr * 64 + m * 32 + cl) * 32 + blkswz;
                ah[m] = *(const short8v*)&LAh[off];
                al[m] = *(const short8v*)&LAl[off];
            }
            #pragma unroll
            for (int n = 0; n < 2; n++) {
                int off = (wc * 64 + n * 32 + cl) * 32 + blkswz;
                bh[n] = *(const short8v*)&LBh[off];
                bl[n] = *(const short8v*)&LBl[off];
            }
            #pragma unroll
            for (int m = 0; m < 2; m++)
                #pragma unroll
                for (int n = 0; n < 2; n++) {
                    acc[m][n] = MFMA32(ah[m], bh[n], acc[m][n]);
                    acc[m][n] = MFMA32(al[m], bh[n], acc[m][n]);
                    acc[m][n] = MFMA32(ah[m], bl[n], acc[m][n]);
                }
        }
    }

    // ---- V-transpose epilogue (MODE3 blocks with col0 >= 1024) ----
    if (MODE == 3 && col0 >= 1024) {
        const int hh = (col0 - 1024) >> 7;
        unsigned* VS = (unsigned*)POOL;       // [32 dd][129] uints
        const int bb0 = row0 / LC;
        const int bound = (bb0 + 1) * LC;
        const int ddl = t >> 3, j0 = (t & 7) * 16;
        #pragma unroll
        for (int p = 0; p < 4; p++) {
            __syncthreads();
            if (wc == (p >> 1)) {
                const int ccl = col0 + wc * 64 + (p & 1) * 32 + cl;
                const float bcol = bias[ccl];
                #pragma unroll
                for (int m = 0; m < 2; m++) {
                    const int lrb = wr * 64 + m * 32 + 4 * kg;
                    #pragma unroll
                    for (int q = 0; q < 4; q++)
                        #pragma unroll
                        for (int r = 0; r < 4; r++) {
                            float v = ((p & 1) ? acc[m][1][q * 4 + r]
                                               : acc[m][0][q * 4 + r]) + bcol;
                            unsigned short hv, lv;
                            split_bf(v, hv, lv);
                            VS[cl * 129 + lrb + 8 * q + r] =
                                (unsigned)hv | ((unsigned)lv << 16);
                        }
                }
            }
            __syncthreads();
            long long vb0 = (long long)((bb0 * HH + hh) * DH + p * 32 + ddl) * VTSTRIDE
                            - (long long)bb0 * LC;
            long long vb1 = (long long)(((bb0 + 1) * HH + hh) * DH + p * 32 + ddl) * VTSTRIDE
                            - (long long)(bb0 + 1) * LC;
            #pragma unroll
            for (int j = 0; j < 16; j++) {
                int row = row0 + j0 + j;
                if (row < M) {
                    long long vi = (row < bound ? vb0 : vb1) + row;
                    Vix[vi] = VS[ddl * 129 + j0 + j];
                }
            }
        }
        return;
    }

    // ---- normal epilogue: col=lane&31, row=(reg&3)+8*(reg>>2)+4*(lane>>5)
    #pragma unroll
    for (int m = 0; m < 2; m++) {
        const int rb = row0 + wr * 64 + m * 32 + 4 * kg;
        #pragma unroll
        for (int n = 0; n < 2; n++) {
            const int cc = col0 + wc * 64 + n * 32 + cl;
            const float bcol = bias[cc];
            #pragma unroll
            for (int q = 0; q < 4; q++) {
                #pragma unroll
                for (int r = 0; r < 4; r++) {
                    int row = rb + 8 * q + r;
                    if (row < M) {
                        float v = acc[m][n][q * 4 + r] + bcol;
                        if (MODE == 1) v += res[(size_t)row * N + cc];
                        if (MODE == 2) {
                            v = gelu_exact(v);
                            unsigned short hv, lv;
                            split_bf(v, hv, lv);
                            Chi[(size_t)row * N + cc] = hv;
                            Clo[(size_t)row * N + cc] = lv;
                        } else if (MODE == 3) {
                            unsigned short hv, lv;
                            split_bf(v, hv, lv);
                            Chi[(size_t)row * 1024 + cc] = hv;
                            Clo[(size_t)row * 1024 + cc] = lv;
                        } else {
                            Cf[(size_t)row * N + cc] = v;
                        }
                    }
                }
            }
        }
    }
}

// ---------------- MFMA flash attention, split-bf16, async-staged ----------
#define AQT 64
#define AKT 32
#define NKT2 17
#define MFMA16(a, b, c) __builtin_amdgcn_mfma_f32_16x16x32_bf16(a, b, c, 0, 0, 0)
__global__ __launch_bounds__(256)
void attn_mfma(const unsigned short* __restrict__ qkhi, const unsigned short* __restrict__ qklo,
               const unsigned* __restrict__ vtx,
               unsigned short* __restrict__ ohi, unsigned short* __restrict__ olo)
{
    __shared__ __align__(16) unsigned short SM[24064];
    #define KH(r,d) SM[(r)*136 + (d)]
    #define KL(r,d) SM[4352 + (r)*136 + (d)]
    #define VH(d,k) SM[8704 + (d)*40 + (k)]
    #define VL(d,k) SM[13824 + (d)*40 + (k)]
    #define PH(r,k) SM[18944 + (r)*40 + (k)]
    #define PL(r,k) SM[21504 + (r)*40 + (k)]
    #define OS(r,d) SM[(r)*136 + (d)]

    const int t = threadIdx.x;
    const int lane = t & 63, w = t >> 6;
    const int id = xcd_swz(blockIdx.x, gridDim.x);
    const int qt = id % 9;
    const int hb = id / 9;
    const int h = hb & 3, b = hb >> 2;
    const int q0 = qt * AQT;
    const int c = lane & 15, g = lane >> 4;
    const float SCALE = 0.08838834764831845f;

    short8v qh[4], ql[4];
    {
        int qrow = b * LC + q0 + w * 16 + c;
        if (qrow > MROWS - 1) qrow = MROWS - 1;
        const unsigned short* bh_ = qkhi + (size_t)qrow * 1024 + h * DH;
        const unsigned short* bl_ = qklo + (size_t)qrow * 1024 + h * DH;
        #pragma unroll
        for (int ks = 0; ks < 4; ks++) {
            qh[ks] = *(const short8v*)(bh_ + ks * 32 + g * 8);
            ql[ks] = *(const short8v*)(bl_ + ks * 32 + g * 8);
        }
    }

    float m_r[4], l_r[4];
    #pragma unroll
    for (int r = 0; r < 4; r++) { m_r[r] = -INFINITY; l_r[r] = 0.f; }
    f32x4 acc_o[8];
    #pragma unroll
    for (int n = 0; n < 8; n++) { acc_o[n][0]=0.f; acc_o[n][1]=0.f; acc_o[n][2]=0.f; acc_o[n][3]=0.f; }

    const int skr = t >> 3, skd = (t & 7) * 16;
    const int svd = t >> 1, svk = (t & 1) * 16;
    const unsigned short* kbase  = qkhi + 512 + h * DH + skd;
    const unsigned short* kbasel = qklo + 512 + h * DH + skd;
    const unsigned* vbase = vtx + ((size_t)((b * HH + h) * DH + svd)) * VTSTRIDE + svk;

    // prologue: stage tile 0 into registers
    short8v rk0, rk1, rl0, rl1;
    uint4 rv0, rv1, rv2, rv3;
    {
        int krow = b * LC + skr; if (krow > MROWS - 1) krow = MROWS - 1;
        const unsigned short* kb  = kbase  + (size_t)krow * 1024;
        const unsigned short* kbl = kbasel + (size_t)krow * 1024;
        rk0 = *(const short8v*)kb;  rk1 = *(const short8v*)(kb + 8);
        rl0 = *(const short8v*)kbl; rl1 = *(const short8v*)(kbl + 8);
        rv0 = *(const uint4*)(vbase);
        rv1 = *(const uint4*)(vbase + 4);
        rv2 = *(const uint4*)(vbase + 8);
        rv3 = *(const uint4*)(vbase + 12);
    }

    for (int kt = 0; kt < NKT2; kt++) {
        __builtin_amdgcn_s_barrier();        // prev iter's K/V readers done
        *(short8v*)&KH(skr, skd)     = rk0;
        *(short8v*)&KH(skr, skd + 8) = rk1;
        *(short8v*)&KL(skr, skd)     = rl0;
        *(short8v*)&KL(skr, skd + 8) = rl1;
        {
            uint4 hA, hB, lA, lB;
            hA.x = (rv0.x & 0xffffu) | (rv0.y << 16);
            hA.y = (rv0.z & 0xffffu) | (rv0.w << 16);
            hA.z = (rv1.x & 0xffffu) | (rv1.y << 16);
            hA.w = (rv1.z & 0xffffu) | (rv1.w << 16);
            hB.x = (rv2.x & 0xffffu) | (rv2.y << 16);
            hB.y = (rv2.z & 0xffffu) | (rv2.w << 16);
            hB.z = (rv3.x & 0xffffu) | (rv3.y << 16);
            hB.w = (rv3.z & 0xffffu) | (rv3.w << 16);
            lA.x = (rv0.x >> 16) | (rv0.y & 0xffff0000u);
            lA.y = (rv0.z >> 16) | (rv0.w & 0xffff0000u);
            lA.z = (rv1.x >> 16) | (rv1.y & 0xffff0000u);
            lA.w = (rv1.z >> 16) | (rv1.w & 0xffff0000u);
            lB.x = (rv2.x >> 16) | (rv2.y & 0xffff0000u);
            lB.y = (rv2.z >> 16) | (rv2.w & 0xffff0000u);
            lB.z = (rv3.x >> 16) | (rv3.y & 0xffff0000u);
            lB.w = (rv3.z >> 16) | (rv3.w & 0xffff0000u);
            *(uint4*)&VH(svd, svk)     = hA;
            *(uint4*)&VH(svd, svk + 8) = hB;
            *(uint4*)&VL(svd, svk)     = lA;
            *(uint4*)&VL(svd, svk + 8) = lB;
        }
        if (kt + 1 < NKT2) {
            int krow = b * LC + (kt + 1) * AKT + skr;
            if (krow > MROWS - 1) krow = MROWS - 1;
            const unsigned short* kb  = kbase  + (size_t)krow * 1024;
            const unsigned short* kbl = kbasel + (size_t)krow * 1024;
            rk0 = *(const short8v*)kb;  rk1 = *(const short8v*)(kb + 8);
            rl0 = *(const short8v*)kbl; rl1 = *(const short8v*)(kbl + 8);
            const unsigned* vb = vbase + (kt + 1) * AKT;
            rv0 = *(const uint4*)(vb);
            rv1 = *(const uint4*)(vb + 4);
            rv2 = *(const uint4*)(vb + 8);
            rv3 = *(const uint4*)(vb + 12);
        }
        asm volatile("s_waitcnt lgkmcnt(0)" ::: "memory");   // my ds_writes done
        __builtin_amdgcn_s_barrier();                        // tile kt fully in LDS
        __builtin_amdgcn_sched_barrier(0);

        f32x4 s[2];
        s[0][0]=s[0][1]=s[0][2]=s[0][3]=0.f;
        s[1][0]=s[1][1]=s[1][2]=s[1][3]=0.f;
        __builtin_amdgcn_s_setprio(1);
        #pragma unroll
        for (int n = 0; n < 2; n++) {
            #pragma unroll
            for (int ks = 0; ks < 4; ks++) {
                short8v kh = *(const short8v*)&KH(n * 16 + c, ks * 32 + g * 8);
                short8v kl = *(const short8v*)&KL(n * 16 + c, ks * 32 + g * 8);
                s[n] = MFMA16(qh[ks], kh, s[n]);
                s[n] = MFMA16(ql[ks], kh, s[n]);
                s[n] = MFMA16(qh[ks], kl, s[n]);
            }
        }
        __builtin_amdgcn_s_setprio(0);

        #pragma unroll
        for (int n = 0; n < 2; n++) {
            bool oob = (kt * 32 + n * 16 + c) >= LC;
            #pragma unroll
            for (int r = 0; r < 4; r++) {
                float sv = s[n][r] * SCALE;
                s[n][r] = oob ? -INFINITY : sv;
            }
        }

        float alpha[4], p0v[4], p1v[4];
        #pragma unroll
        for (int r = 0; r < 4; r++) {
            float rm = fmaxf(s[0][r], s[1][r]);
            #pragma unroll
            for (int off = 1; off < 16; off <<= 1) rm = fmaxf(rm, __shfl_xor(rm, off));
            float mn = fmaxf(m_r[r], rm);
            float p0 = expf(s[0][r] - mn);
            float p1 = expf(s[1][r] - mn);
            float ts = p0 + p1;
            #pragma unroll
            for (int off = 1; off < 16; off <<= 1) ts += __shfl_xor(ts, off);
            float al = expf(m_r[r] - mn);
            m_r[r] = mn;
            l_r[r] = al * l_r[r] + ts;
            alpha[r] = al;
            p0v[r] = p0; p1v[r] = p1;
        }

        #pragma unroll
        for (int n = 0; n < 8; n++)
            #pragma unroll
            for (int r = 0; r < 4; r++) acc_o[n][r] *= alpha[r];

        // P write + read: wave-private LDS rows, in-order LDS pipe -> no barrier
        #pragma unroll
        for (int r = 0; r < 4; r++) {
            unsigned short ph, pl;
            split_bf(p0v[r], ph, pl);
            PH(w * 16 + g * 4 + r, c) = ph;
            PL(w * 16 + g * 4 + r, c) = pl;
            split_bf(p1v[r], ph, pl);
            PH(w * 16 + g * 4 + r, 16 + c) = ph;
            PL(w * 16 + g * 4 + r, 16 + c) = pl;
        }
        short8v pah = *(const short8v*)&PH(w * 16 + c, g * 8);
        short8v pal = *(const short8v*)&PL(w * 16 + c, g * 8);
        __builtin_amdgcn_s_setprio(1);
        #pragma unroll
        for (int n = 0; n < 8; n++) {
            short8v vh = *(const short8v*)&VH(n * 16 + c, g * 8);
            short8v vl = *(const short8v*)&VL(n * 16 + c, g * 8);
            acc_o[n] = MFMA16(pah, vh, acc_o[n]);
            acc_o[n] = MFMA16(pal, vh, acc_o[n]);
            acc_o[n] = MFMA16(pah, vl, acc_o[n]);
        }
        __builtin_amdgcn_s_setprio(0);
    }

    float inv[4];
    #pragma unroll
    for (int r = 0; r < 4; r++) inv[r] = 1.0f / l_r[r];

    const int orow = t >> 2, oc0 = (t & 3) * 32;
    #pragma unroll
    for (int pass = 0; pass < 2; pass++) {
        __syncthreads();
        #pragma unroll
        for (int n = 0; n < 8; n++)
            #pragma unroll
            for (int r = 0; r < 4; r++) {
                float v = acc_o[n][r] * inv[r];
                unsigned short hv, lv;
                split_bf(v, hv, lv);
                OS(w * 16 + g * 4 + r, n * 16 + c) = pass ? lv : hv;
            }
        __syncthreads();
        int grow = q0 + orow;
        if (grow < LC) {
            unsigned short* dst = (pass ? olo : ohi) + ((size_t)(b * LC + grow)) * DD + h * DH + oc0;
            #pragma unroll
            for (int u = 0; u < 4; u++)
                *(short8v*)(dst + u * 8) = *(const short8v*)&OS(orow, oc0 + u * 8);
        }
    }
    #undef KH
    #undef KL
    #undef VH
    #undef VL
    #undef PH
    #undef PL
    #undef OS
}

// ---------------- LayerNorm over 512 (wave per row) ----------------
__global__ __launch_bounds__(256)
void ln512(const float* __restrict__ X, const float* __restrict__ g,
           const float* __restrict__ bb, float* __restrict__ Y,
           unsigned short* __restrict__ Yhi, unsigned short* __restrict__ Ylo)
{
    int row = blockIdx.x * 4 + (threadIdx.x >> 6);
    int lane = threadIdx.x & 63;
    const float* x = X + (size_t)row * DD + lane * 8;
    float4 v0 = *(const float4*)x;
    float4 v1 = *(const float4*)(x + 4);
    float vv[8] = {v0.x,v0.y,v0.z,v0.w,v1.x,v1.y,v1.z,v1.w};
    float s = 0.f;
    #pragma unroll
    for (int i = 0; i < 8; i++) s += vv[i];
    #pragma unroll
    for (int off = 1; off < 64; off <<= 1) s += __shfl_xor(s, off);
    float mean = s * (1.0f / 512.0f);
    float d[8], s2 = 0.f;
    #pragma unroll
    for (int i = 0; i < 8; i++) { d[i] = vv[i] - mean; s2 += d[i] * d[i]; }
    #pragma unroll
    for (int off = 1; off < 64; off <<= 1) s2 += __shfl_xor(s2, off);
    float var = s2 * (1.0f / 512.0f);
    float rstd = 1.0f / sqrtf(var + 1e-5f);
    float4 g0 = *(const float4*)(g + lane * 8);
    float4 g1 = *(const float4*)(g + lane * 8 + 4);
    float4 b0 = *(const float4*)(bb + lane * 8);
    float4 b1 = *(const float4*)(bb + lane * 8 + 4);
    float gg[8] = {g0.x,g0.y,g0.z,g0.w,g1.x,g1.y,g1.z,g1.w};
    float bv[8] = {b0.x,b0.y,b0.z,b0.w,b1.x,b1.y,b1.z,b1.w};
    float ov[8];
    unsigned short hs[8], ls[8];
    #pragma unroll
    for (int i = 0; i < 8; i++) {
        ov[i] = d[i] * rstd * gg[i] + bv[i];
        split_bf(ov[i], hs[i], ls[i]);
    }
    size_t o = (size_t)row * DD + lane * 8;
    *(float4*)(Y + o)     = make_float4(ov[0], ov[1], ov[2], ov[3]);
    *(float4*)(Y + o + 4) = make_float4(ov[4], ov[5], ov[6], ov[7]);
    uint4 hv, lv;
    hv.x = (unsigned)hs[0] | ((unsigned)hs[1] << 16);
    hv.y = (unsigned)hs[2] | ((unsigned)hs[3] << 16);
    hv.z = (unsigned)hs[4] | ((unsigned)hs[5] << 16);
    hv.w = (unsigned)hs[6] | ((unsigned)hs[7] << 16);
    lv.x = (unsigned)ls[0] | ((unsigned)ls[1] << 16);
    lv.y = (unsigned)ls[2] | ((unsigned)ls[3] << 16);
    lv.z = (unsigned)ls[4] | ((unsigned)ls[5] << 16);
    lv.w = (unsigned)ls[6] | ((unsigned)ls[7] << 16);
    *(uint4*)(Yhi + o) = hv;
    *(uint4*)(Ylo + o) = lv;
}

// ---------------- mean over L (two-pass) ----------------
__global__ __launch_bounds__(128)
void mean_part(const float* __restrict__ query, float* __restrict__ part)
{
    int b = blockIdx.x, ch = blockIdx.y, t = threadIdx.x;
    const float* base = query + ((size_t)b * LQ + ch * 64) * DD + t * 4;
    float ax = 0.f, ay = 0.f, az = 0.f, aw = 0.f;
    for (int l = 0; l < 64; l++) {
        float4 v = *(const float4*)(base + (size_t)l * DD);
        ax += v.x; ay += v.y; az += v.z; aw += v.w;
    }
    *(float4*)(part + ((size_t)(b * 8 + ch)) * DD + t * 4) = make_float4(ax, ay, az, aw);
}

__global__ __launch_bounds__(128)
void mean_fin(const float* __restrict__ part, float* __restrict__ xm)
{
    int b = blockIdx.x, t = threadIdx.x;
    float ax = 0.f, ay = 0.f, az = 0.f, aw = 0.f;
    #pragma unroll
    for (int ch = 0; ch < 8; ch++) {
        float4 v = *(const float4*)(part + ((size_t)(b * 8 + ch)) * DD + t * 4);
        ax += v.x; ay += v.y; az += v.z; aw += v.w;
    }
    *(float4*)(xm + (size_t)b * DD + t * 4) =
        make_float4(ax * (1.f/512.f), ay * (1.f/512.f), az * (1.f/512.f), aw * (1.f/512.f));
}

static __device__ __forceinline__ float block128_sum(float x, float* red, int t) {
    #pragma unroll
    for (int off = 1; off < 64; off <<= 1) x += __shfl_xor(x, off);
    if ((t & 63) == 0) red[t >> 6] = x;
    __syncthreads();
    float r = red[0] + red[1];
    __syncthreads();
    return r;
}

// ---------------- proj + LN -> q_repr ----------------
__global__ __launch_bounds__(128)
void proj_ln(const float* __restrict__ h, const float* __restrict__ pW, const float* __restrict__ pb,
             const float* __restrict__ pg, const float* __restrict__ pbb, float* __restrict__ q_repr)
{
    __shared__ float xs[DD];
    __shared__ float red[2];
    int b = blockIdx.x, t = threadIdx.x;
    *(float4*)&xs[t * 4] = *(const float4*)(h + (size_t)(b * LC) * DD + t * 4);
    __syncthreads();
    const float* w = pW + (size_t)t * DD;
    float acc = pb[t];
    for (int k = 0; k < DD; k += 4) {
        float4 a = *(const float4*)&xs[k];
        float4 ww = *(const float4*)(w + k);
        acc += a.x * ww.x + a.y * ww.y + a.z * ww.z + a.w * ww.w;
    }
    float mean = block128_sum(acc, red, t) * (1.f / 128.f);
    float dx = acc - mean;
    float var = block128_sum(dx * dx, red, t) * (1.f / 128.f);
    float rstd = 1.0f / sqrtf(var + 1e-5f);
    q_repr[(size_t)b * DRr + t] = dx * rstd * pg[t] + pbb[t];
}

// ---------------- value encoder (fused) -> q_val ----------------
__global__ __launch_bounds__(128)
void venc(const float* __restrict__ xm, const float* __restrict__ vW1, const float* __restrict__ vb1,
          const float* __restrict__ vg, const float* __restrict__ vb,
          const float* __restrict__ vW2, const float* __restrict__ vb2,
          float* __restrict__ q_val)
{
    __shared__ float xs[DD];
    __shared__ float hg[DRr];
    __shared__ float red[2];
    int b = blockIdx.x, t = threadIdx.x;
    *(float4*)&xs[t * 4] = *(const float4*)(xm + (size_t)b * DD + t * 4);
    __syncthreads();
    const float* w = vW1 + (size_t)t * DD;
    float acc = vb1[t];
    for (int k = 0; k < DD; k += 4) {
        float4 a = *(const float4*)&xs[k];
        float4 ww = *(const float4*)(w + k);
        acc += a.x * ww.x + a.y * ww.y + a.z * ww.z + a.w * ww.w;
    }
    float mean = block128_sum(acc, red, t) * (1.f / 128.f);
    float dx = acc - mean;
    float var = block128_sum(dx * dx, red, t) * (1.f / 128.f);
    float rstd = 1.0f / sqrtf(var + 1e-5f);
    float hn = dx * rstd * vg[t] + vb[t];
    hg[t] = gelu_exact(hn);
    __syncthreads();
    const float* w2 = vW2 + (size_t)t * DRr;
    float acc2 = vb2[t];
    for (int k = 0; k < DRr; k += 4) {
        float4 a = *(const float4*)&hg[k];
        float4 ww = *(const float4*)(w2 + k);
        acc2 += a.x * ww.x + a.y * ww.y + a.z * ww.z + a.w * ww.w;
    }
    q_val[(size_t)b * DRr + t] = acc2;
}

// ---------------- combine ----------------
__global__ void combine_qk(const float* __restrict__ qr, const float* __restrict__ qv,
                           const float* __restrict__ swp, float* __restrict__ qk)
{
    int i = blockIdx.x * blockDim.x + threadIdx.x;
    if (i < B_ * DRr) {
        float sw = swp[0];
        qk[i] = sw * qr[i] + (1.f - sw) * qv[i];
    }
}

// ---------------- sim ----------------
#define SIMCH 10
__global__ __launch_bounds__(256)
void sim_kernel(const float* __restrict__ qk, const float* __restrict__ mkeys, float* __restrict__ sim)
{
    __shared__ float qs[DRr];
    int b = blockIdx.x, ch = blockIdx.y, t = threadIdx.x;
    if (t < DRr) qs[t] = qk[(size_t)b * DRr + t];
    __syncthreads();
    float qn = 0.f;
    #pragma unroll 8
    for (int i = 0; i < DRr; i++) qn += qs[i] * qs[i];
    int n0 = ch * (NKEYS / SIMCH), n1 = n0 + (NKEYS / SIMCH);
    for (int n = n0 + t; n < n1; n += 256) {
        const float* kr = mkeys + (size_t)n * DRr;
        float dot = 0.f, kn = 0.f;
        #pragma unroll 8
        for (int i = 0; i < DRr; i += 4) {
            float4 kv = *(const float4*)(kr + i);
            dot += qs[i] * kv.x + qs[i + 1] * kv.y + qs[i + 2] * kv.z + qs[i + 3] * kv.w;
            kn  += kv.x * kv.x + kv.y * kv.y + kv.z * kv.z + kv.w * kv.w;
        }
        float d = qn - 2.f * dot + kn;
        sim[(size_t)b * NKEYS + n] = -d / 0.1f;
    }
}

// ---------------- top-k (jax semantics: value desc, ties -> lower index) ----
static __device__ __forceinline__ void topk_insert(float* v, int* id, float x, int n) {
    bool better = (x > v[TOPK - 1]) || (x == v[TOPK - 1] && n < id[TOPK - 1]);
    if (better) {
        v[TOPK - 1] = x; id[TOPK - 1] = n;
        #pragma unroll
        for (int k = TOPK - 1; k > 0; k--) {
            bool sw = (v[k] > v[k - 1]) || (v[k] == v[k - 1] && id[k] < id[k - 1]);
            if (!sw) break;
            float tv = v[k]; v[k] = v[k - 1]; v[k - 1] = tv;
            int ti = id[k]; id[k] = id[k - 1]; id[k - 1] = ti;
        }
    }
}

__global__ __launch_bounds__(256)
void topk_kernel(const float* __restrict__ sim, int* __restrict__ topidx, float* __restrict__ wout)
{
    __shared__ float sv[256][TOPK];
    __shared__ int   si[256][TOPK];
    int b = blockIdx.x, t = threadIdx.x;
    float v[TOPK]; int id[TOPK];
    #pragma unroll
    for (int k = 0; k < TOPK; k++) { v[k] = -INFINITY; id[k] = 0x7fffffff; }
    for (int n = t; n < NKEYS; n += 256) {
        topk_insert(v, id, sim[(size_t)b * NKEYS + n], n);
    }
    #pragma unroll
    for (int k = 0; k < TOPK; k++) { sv[t][k] = v[k]; si[t][k] = id[k]; }
    for (int strd = 128; strd >= 1; strd >>= 1) {
        __syncthreads();
        if (t < strd) {
            #pragma unroll
            for (int k = 0; k < TOPK; k++) topk_insert(v, id, sv[t + strd][k], si[t + strd][k]);
            #pragma unroll
            for (int k = 0; k < TOPK; k++) { sv[t][k] = v[k]; si[t][k] = id[k]; }
        }
    }
    if (t == 0) {
        float m = v[0];
        float e[TOPK]; float sum = 0.f;
        #pragma unroll
        for (int k = 0; k < TOPK; k++) { e[k] = expf(v[k] - m); sum += e[k]; }
        #pragma unroll
        for (int k = 0; k < TOPK; k++) {
            wout[(size_t)b * TOPK + k] = e[k] / sum;
            topidx[b * TOPK + k] = id[k];
        }
    }
}

// ---------------- gather ----------------
__global__ __launch_bounds__(128)
void gather_kernel(const float* __restrict__ mv, const int* __restrict__ topidx, float* __restrict__ out)
{
    int blk = blockIdx.x;
    int b = blk / (TOPK * PP);
    int rem = blk - b * (TOPK * PP);
    int k = rem / PP;
    int p = rem - k * PP;
    int idx = topidx[b * TOPK + k];
    const float4* src = (const float4*)(mv + ((size_t)idx * PP + p) * DD);
    float4* dst = (float4*)(out + (size_t)blk * DD);
    dst[threadIdx.x] = src[threadIdx.x];
}

// ---------------- launch ----------------
extern "C" void kernel_launch(void* const* d_in, const int* in_sizes, int n_in,
                              void* d_out, int out_size, void* d_ws, size_t ws_size,
                              hipStream_t stream) {
    const float* query = (const float*)d_in[0];
    const float* mkeys = (const float*)d_in[1];
    const float* mvals = (const float*)d_in[2];
    const float* cls   = (const float*)d_in[3];
    const float* Wqkv  = (const float*)d_in[4];
    const float* bqkv  = (const float*)d_in[5];
    const float* Wo    = (const float*)d_in[6];
    const float* bo    = (const float*)d_in[7];
    const float* ln1g  = (const float*)d_in[8];
    const float* ln1b  = (const float*)d_in[9];
    const float* W1    = (const float*)d_in[10];
    const float* b1    = (const float*)d_in[11];
    const float* W2    = (const float*)d_in[12];
    const float* b2    = (const float*)d_in[13];
    const float* ln2g  = (const float*)d_in[14];
    const float* ln2b  = (const float*)d_in[15];
    const float* pW    = (const float*)d_in[16];
    const float* pb    = (const float*)d_in[17];
    const float* pg    = (const float*)d_in[18];
    const float* pbb   = (const float*)d_in[19];
    const float* vW1   = (const float*)d_in[20];
    const float* vb1   = (const float*)d_in[21];
    const float* vg    = (const float*)d_in[22];
    const float* vb    = (const float*)d_in[23];
    const float* vW2   = (const float*)d_in[24];
    const float* vb2   = (const float*)d_in[25];
    const float* swp   = (const float*)d_in[26];
    float* out = (float*)d_out;

    // ---- workspace layout ----
    float* ws    = (float*)d_ws;
    float* h     = ws;
    float* preln = h + (size_t)MROWS * DD;
    unsigned short* h_hi  = (unsigned short*)(preln + (size_t)MROWS * DD);
    unsigned short* h_lo  = h_hi  + (size_t)MROWS * DD;
    unsigned short* mid_hi = h_lo + (size_t)MROWS * DD;
    unsigned short* mid_lo = mid_hi + (size_t)MROWS * 1024;
    unsigned short* qkhi  = mid_lo + (size_t)MROWS * 1024;
    unsigned short* qklo  = qkhi  + (size_t)MROWS * 1024;
    unsigned* vtx         = (unsigned*)(qklo + (size_t)MROWS * 1024);
    unsigned short* wq_hi = (unsigned short*)(vtx + (size_t)32768 * VTSTRIDE);
    unsigned short* wq_lo = wq_hi + (size_t)2 * 1536 * DD;
    unsigned short* wo_hi = wq_lo + (size_t)2 * 1536 * DD;
    unsigned short* wo_lo = wo_hi + (size_t)2 * DD * DD;
    unsigned short* w1_hi = wo_lo + (size_t)2 * DD * DD;
    unsigned short* w1_lo = w1_hi + (size_t)2 * 1024 * DD;
    unsigned short* w2_hi = w1_lo + (size_t)2 * 1024 * DD;
    unsigned short* w2_lo = w2_hi + (size_t)2 * DD * 1024;
    float* xm   = (float*)(w2_lo + (size_t)2 * DD * 1024);
    float* qval = xm   + (size_t)B_ * DD;
    float* qrep = qval + (size_t)B_ * DRr;
    float* qkc  = qrep + (size_t)B_ * DRr;
    float* simb = qkc  + (size_t)B_ * DRr;
    int*   tidx = (int*)(simb + (size_t)B_ * NKEYS);
    float* mpart = (float*)(tidx + 512);
    (void)ws_size; (void)in_sizes; (void)n_in; (void)out_size;

    // ---- weight splits ----
    {
        int n4;
        n4 = 2 * 1536 * DD / 4;
        split_kernel<<<(n4 + 255) / 256, 256, 0, stream>>>(Wqkv, wq_hi, wq_lo, n4);
        n4 = 2 * DD * DD / 4;
        split_kernel<<<(n4 + 255) / 256, 256, 0, stream>>>(Wo, wo_hi, wo_lo, n4);
        n4 = 2 * 1024 * DD / 4;
        split_kernel<<<(n4 + 255) / 256, 256, 0, stream>>>(W1, w1_hi, w1_lo, n4);
        n4 = 2 * DD * 1024 / 4;
        split_kernel<<<(n4 + 255) / 256, 256, 0, stream>>>(W2, w2_hi, w2_lo, n4);
    }

    concat_cls<<<MROWS / 4, 256, 0, stream>>>(query, cls, h, h_hi, h_lo);

    for (int l = 0; l < 2; l++) {
        const unsigned short* wqh = wq_hi + (size_t)l * 1536 * DD;
        const unsigned short* wql = wq_lo + (size_t)l * 1536 * DD;
        const unsigned short* woh = wo_hi + (size_t)l * DD * DD;
        const unsigned short* wol = wo_lo + (size_t)l * DD * DD;
        const unsigned short* w1h = w1_hi + (size_t)l * 1024 * DD;
        const unsigned short* w1l = w1_lo + (size_t)l * 1024 * DD;
        const unsigned short* w2h = w2_hi + (size_t)l * DD * 1024;
        const unsigned short* w2l = w2_lo + (size_t)l * DD * 1024;
        const float* bq  = bqkv + (size_t)l * 1536;
        const float* bol = bo   + (size_t)l * DD;
        const float* g1  = ln1g + (size_t)l * DD;
        const float* be1 = ln1b + (size_t)l * DD;
        const float* b1l = b1   + (size_t)l * 1024;
        const float* b2l = b2   + (size_t)l * DD;
        const float* g2  = ln2g + (size_t)l * DD;
        const float* be2 = ln2b + (size_t)l * DD;

        // QKV -> qk splits + transposed interleaved V
        gemm3<3><<<257 * 12, 256, 0, stream>>>(h_hi, h_lo, wqh, wql, bq, nullptr,
                                               nullptr, qkhi, qklo, vtx,
                                               MROWS, 1536, DD, 12);
        // MFMA attention -> h_hi/h_lo (attn-out splits)
        attn_mfma<<<9 * HH * B_, 256, 0, stream>>>(qkhi, qklo, vtx, h_hi, h_lo);
        // Wo + residual -> preln fp32
        gemm3<1><<<257 * 4, 256, 0, stream>>>(h_hi, h_lo, woh, wol, bol, h,
                                              preln, nullptr, nullptr, nullptr,
                                              MROWS, DD, DD, 4);
        ln512<<<MROWS / 4, 256, 0, stream>>>(preln, g1, be1, h, h_hi, h_lo);
        // FFN1 + gelu -> mid splits
        gemm3<2><<<257 * 8, 256, 0, stream>>>(h_hi, h_lo, w1h, w1l, b1l, nullptr,
                                              nullptr, mid_hi, mid_lo, nullptr,
                                              MROWS, 1024, DD, 8);
        // FFN2 + residual -> preln fp32
        gemm3<1><<<257 * 4, 256, 0, stream>>>(mid_hi, mid_lo, w2h, w2l, b2l, h,
                                              preln, nullptr, nullptr, nullptr,
                                              MROWS, DD, 1024, 4);
        ln512<<<MROWS / 4, 256, 0, stream>>>(preln, g2, be2, h, h_hi, h_lo);
    }

    proj_ln<<<B_, 128, 0, stream>>>(h, pW, pb, pg, pbb, qrep);
    mean_part<<<dim3(B_, 8), 128, 0, stream>>>(query, mpart);
    mean_fin<<<B_, 128, 0, stream>>>(mpart, xm);
    venc<<<B_, 128, 0, stream>>>(xm, vW1, vb1, vg, vb, vW2, vb2, qval);
    combine_qk<<<(B_ * DRr + 255) / 256, 256, 0, stream>>>(qrep, qval, swp, qkc);
    sim_kernel<<<dim3(B_, SIMCH), 256, 0, stream>>>(qkc, mkeys, simb);
    topk_kernel<<<B_, 256, 0, stream>>>(simb, tidx, out + (size_t)B_ * TOPK * PP * DD);
    gather_kernel<<<B_ * TOPK * PP, 128, 0, stream>>>(mvals, tidx, out);
}